// Round 11
// baseline (137.712 us; speedup 1.0000x reference)
//
#include <hip/hip_runtime.h>

// SNN forward — R15: R14 + RPL=1 (shorter chains, 2x waves) + late colmax.
//
// Score decomposition: fill ~51us (harness) + kernel ~35-45us + ~45us
// launch overhead. Kernel VALU issue is only ~5-8us -> residual is per-wave
// LATENCY CHAINS x block turnover. R15 shortens the chain:
//  - RPL 2->1: halves x-load count, layer-1 chain (160->80 packed FMA),
//    gate count; doubles wave count (finer pipelining, shorter tail);
//    halves cooperative-entry probability per wave.
//  - colmax shuffle-reduce moved AFTER layer-1 (its only consumer is the
//    gates): the W2 vmcnt-wait now hides under ~200 layer-1 instructions
//    instead of stalling the wave up front.
//  - zero-burst issued FIRST (depends only on wt0).
//
// All forms verbatim-verified (absmax 0.0): packed-v2f layer-1 chain
// (R6/R7/R12/R14), shuffle-tree colmax (R14; fmax exactly associative ->
// identical values), gate-1/gate-2 (R5-R12; fp sum err <= 31*2^-24*
// Sum|terms| ~ 4e-5 << 2e-3 margin), cooperative dense path (R11/R12/R14;
// predicated +0.0 IEEE identity, ascending i), serial tail (R4-R14).

typedef float v4f __attribute__((ext_vector_type(4)));
typedef float v2f __attribute__((ext_vector_type(2)));

#define TPB 256
#define TROWS 64               // rows per wave (1 per lane)
#define RPB (TPB * 1)          // 256 rows per block

__global__ __launch_bounds__(TPB) void snn_one(
    const float* __restrict__ x,
    const float* __restrict__ W1,   // [32,5]
    const float* __restrict__ W2,   // [32,32]
    const float* __restrict__ W3,   // [16,32]
    const float* __restrict__ W4,   // [10,16]
    float* __restrict__ out,        // [B,10]
    int B)
{
    __shared__ __align__(16) float xsh[4][TROWS * 5];   // 5KB: wave-private x
    __shared__ __align__(16) float smxl[4][32];         // per-wave colmax

    const int t = threadIdx.x;
    const int wv = t >> 6, lane = t & 63;
    float* sb = xsh[wv];
    const long wt0 = (long)blockIdx.x * RPB + (long)wv * TROWS;
    if (wt0 >= B) return;

    const bool full = (wt0 + TROWS <= B);

    // ---- (1) EARLY coalesced zero-burst: depends only on wt0 ----
    if (full) {
        v4f z = {0.0f, 0.0f, 0.0f, 0.0f};
        v4f* og = (v4f*)(out + wt0 * 10);
        og[lane] = z;
        og[64 + lane] = z;
        if (lane < 32) og[128 + lane] = z;   // 160 v4f = 640 floats
    }

    // ---- (2) x loads: 320 floats = 80 v4f ----
    v4f g0, g1;
    if (full) {
        const v4f* xg = (const v4f*)(x + wt0 * 5);
        g0 = xg[lane];
        if (lane < 16) g1 = xg[64 + lane];
    }

    // ---- (3) W2 coalesced loads (consumed late, after layer-1) ----
    v4f wm0, wm1, wm2, wm3;
    {
        const v4f* w2g = (const v4f*)W2;
        wm0 = w2g[lane];
        wm1 = w2g[64 + lane];
        wm2 = w2g[128 + lane];
        wm3 = w2g[192 + lane];
    }

    if (full) {
        // ---- (4) stage x -> wave-private LDS, read back own row ----
        v4f* s4 = (v4f*)sb;
        s4[lane] = g0;
        if (lane < 16) s4[64 + lane] = g1;

        float xf[5];
        {
            const float* sx = sb + lane * 5;   // stride-5 banks: 2-way, free
#pragma unroll
            for (int e = 0; e < 5; ++e) xf[e] = sx[e];
        }

        // ---- (5) layer 1: packed v2f, j2-outer (verified form) ----
        unsigned m = 0u;
#pragma unroll
        for (int j2 = 0; j2 < 16; ++j2) {
            const float* wA = W1 + (2 * j2) * 5;
            const float* wB = W1 + (2 * j2 + 1) * 5;
            const v2f w0 = {wA[0], wB[0]};
            const v2f w1 = {wA[1], wB[1]};
            const v2f w2 = {wA[2], wB[2]};
            const v2f w3 = {wA[3], wB[3]};
            const v2f w4 = {wA[4], wB[4]};
            v2f h = xf[0] * w0;   // exact per-neuron chain order
            h += xf[1] * w1;
            h += xf[2] * w2;
            h += xf[3] * w3;
            h += xf[4] * w4;
            if (h.x >= 2.0f) m |= (1u << (2 * j2));
            if (h.y >= 2.0f) m |= (1u << (2 * j2 + 1));
        }

        // ---- (6) colmax shuffle tree (W2 latency now hidden) ----
        float mxmax;
        {
            v4f vm;
            vm.x = fmaxf(fmaxf(wm0.x, wm1.x), fmaxf(wm2.x, wm3.x));
            vm.y = fmaxf(fmaxf(wm0.y, wm1.y), fmaxf(wm2.y, wm3.y));
            vm.z = fmaxf(fmaxf(wm0.z, wm1.z), fmaxf(wm2.z, wm3.z));
            vm.w = fmaxf(fmaxf(wm0.w, wm1.w), fmaxf(wm2.w, wm3.w));
#pragma unroll
            for (int off = 8; off <= 32; off <<= 1) {
                vm.x = fmaxf(vm.x, __shfl_xor(vm.x, off));
                vm.y = fmaxf(vm.y, __shfl_xor(vm.y, off));
                vm.z = fmaxf(vm.z, __shfl_xor(vm.z, off));
                vm.w = fmaxf(vm.w, __shfl_xor(vm.w, off));
            }
            if (lane < 8) *(v4f*)(&smxl[wv][4 * lane]) = vm;
            float mx = fmaxf(fmaxf(vm.x, vm.y), fmaxf(vm.z, vm.w));
#pragma unroll
            for (int off = 1; off <= 4; off <<= 1)
                mx = fmaxf(mx, __shfl_xor(mx, off));
            mxmax = mx;
        }
        const float* __restrict__ smx = smxl[wv];

        // ---- (7) gates (verbatim R12/R14 form) ----
        bool dense = false;
        if (m && ((float)__popc(m) * mxmax >= 1.998f)) {
            float S = 0.0f;
            unsigned mm = m;
            while (mm) { int i = __ffs(mm) - 1; mm &= mm - 1; S += smx[i]; }
            dense = (S >= 1.998f);
        }

        // ---- (8) cooperative dense path (verbatim R11/R12/R14) ----
        if (__any(dense)) {
            v4f w2r[8];
            {
                const v4f* wr = (const v4f*)(W2 + (lane & 31) * 32);
#pragma unroll
                for (int e = 0; e < 8; ++e) w2r[e] = wr[e];
            }
            const float* w2f = (const float*)w2r;

            unsigned long long dmask = __ballot(dense);
            while (dmask) {
                const int L = (int)__ffsll(dmask) - 1;
                dmask &= dmask - 1;
                const unsigned mrow = __shfl(m, L);   // uniform bcast

                // h2[j] for j=lane (lanes 0..31), ascending i,
                // predicated +0.0 identity == verified skip form
                float h2 = 0.0f;
#pragma unroll
                for (int i = 0; i < 32; ++i)
                    h2 += ((mrow >> i) & 1u) ? w2f[i] : 0.0f;
                const unsigned m2 =
                    (unsigned)__ballot(lane < 32 && h2 >= 2.0f);

                if (m2) {   // ultra-rare
                    float g3 = 0.0f;
                    if (lane < 16) {
                        const float* w3r = W3 + lane * 32;
#pragma unroll
                        for (int i = 0; i < 32; ++i)
                            g3 += ((m2 >> i) & 1u) ? w3r[i] : 0.0f;
                    }
                    const unsigned m3 =
                        (unsigned)__ballot(lane < 16 && g3 >= 2.0f);
                    if (m3) {
                        float g4 = 0.0f;
                        if (lane < 10) {
                            const float* w4r = W4 + lane * 16;
#pragma unroll
                            for (int i = 0; i < 16; ++i)
                                g4 += ((m3 >> i) & 1u) ? w4r[i] : 0.0f;
                        }
                        __builtin_amdgcn_s_waitcnt(0);  // order vs zero-burst
                        if (lane < 10)
                            out[(wt0 + (long)L) * 10 + lane] =
                                (g4 >= 2.0f) ? 1.0f : 0.0f;
                    }
                }
            }
        }
    } else {
        // ---- tail wave (not hit at B=2^21; correctness-general, serial) ----
        // colmax for tail: serial exact form (cheap; tail is one wave)
        float mxmax;
        {
            v4f vm;
            vm.x = fmaxf(fmaxf(wm0.x, wm1.x), fmaxf(wm2.x, wm3.x));
            vm.y = fmaxf(fmaxf(wm0.y, wm1.y), fmaxf(wm2.y, wm3.y));
            vm.z = fmaxf(fmaxf(wm0.z, wm1.z), fmaxf(wm2.z, wm3.z));
            vm.w = fmaxf(fmaxf(wm0.w, wm1.w), fmaxf(wm2.w, wm3.w));
#pragma unroll
            for (int off = 8; off <= 32; off <<= 1) {
                vm.x = fmaxf(vm.x, __shfl_xor(vm.x, off));
                vm.y = fmaxf(vm.y, __shfl_xor(vm.y, off));
                vm.z = fmaxf(vm.z, __shfl_xor(vm.z, off));
                vm.w = fmaxf(vm.w, __shfl_xor(vm.w, off));
            }
            float mx = fmaxf(fmaxf(vm.x, vm.y), fmaxf(vm.z, vm.w));
#pragma unroll
            for (int off = 1; off <= 4; off <<= 1)
                mx = fmaxf(mx, __shfl_xor(mx, off));
            mxmax = mx;
        }

        const long r = wt0 + (long)lane;
        if (r < B) {
            float xr[5];
#pragma unroll
            for (int k = 0; k < 5; ++k) xr[k] = x[r * 5 + k];
            unsigned mc = 0u;
#pragma unroll
            for (int j = 0; j < 32; ++j) {
                const float* w = W1 + j * 5;
                float h = xr[0] * w[0];
                h += xr[1] * w[1];
                h += xr[2] * w[2];
                h += xr[3] * w[3];
                h += xr[4] * w[4];
                if (h >= 2.0f) mc |= (1u << j);
            }
            float o[10];
#pragma unroll
            for (int j = 0; j < 10; ++j) o[j] = 0.0f;
            if (mc && ((float)__popc(mc) * mxmax >= 1.998f)) {
                // serial dense: VERBATIM verified ascending set-bit order
                float h2[32];
#pragma unroll
                for (int j = 0; j < 32; ++j) h2[j] = 0.0f;
                unsigned mm = mc;
                while (mm) {
                    const int i = __ffs(mm) - 1;
                    mm &= mm - 1;
                    const float* colp = W2 + i;   // W2^T[i][j] == W2[j*32+i]
#pragma unroll
                    for (int j = 0; j < 32; ++j) h2[j] += colp[j * 32];
                }
                unsigned m2 = 0u;
#pragma unroll
                for (int j = 0; j < 32; ++j)
                    if (h2[j] >= 2.0f) m2 |= (1u << j);
                if (m2) {
                    unsigned m3 = 0u;
#pragma unroll
                    for (int j = 0; j < 16; ++j) {
                        float gg = 0.0f;
#pragma unroll
                        for (int i = 0; i < 32; ++i)
                            if ((m2 >> i) & 1u) gg += W3[j * 32 + i];
                        if (gg >= 2.0f) m3 |= (1u << j);
                    }
#pragma unroll
                    for (int j = 0; j < 10; ++j) {
                        float gg = 0.0f;
#pragma unroll
                        for (int i = 0; i < 16; ++i)
                            if ((m3 >> i) & 1u) gg += W4[j * 16 + i];
                        o[j] = (gg >= 2.0f) ? 1.0f : 0.0f;
                    }
                }
            }
#pragma unroll
            for (int j = 0; j < 10; ++j) out[r * 10 + j] = o[j];
        }
    }
}

extern "C" void kernel_launch(void* const* d_in, const int* in_sizes, int n_in,
                              void* d_out, int out_size, void* d_ws, size_t ws_size,
                              hipStream_t stream) {
    const float* x  = (const float*)d_in[0];
    const float* W1 = (const float*)d_in[1];
    const float* W2 = (const float*)d_in[2];
    const float* W3 = (const float*)d_in[3];
    const float* W4 = (const float*)d_in[4];
    float* out = (float*)d_out;

    int B = in_sizes[0] / 5;
    int grid = (B + RPB - 1) / RPB;
    snn_one<<<grid, TPB, 0, stream>>>(x, W1, W2, W3, W4, out, B);
}

// Round 12
// 133.855 us; speedup vs baseline: 1.0288x; 1.0288x over previous
//
#include <hip/hip_runtime.h>

// SNN forward — R16: hipMemsetAsync writes the zeros; kernel writes ONLY
// dense rows.
//
// R15 post-mortem: kernel pinned at ~45us across 4 structural variants.
// Cause: the kernel is a bad memset engine -- each wave issues 2.5-5 store
// instrs between ~2us latency chains, draining the 82MB zero-stream at
// ~1.9 TB/s (43us), while the harness's own fillBufferAligned does 6.5 TB/s.
// 97% of output bytes are zero. R16 moves the zero-write to a stream-ordered
// hipMemsetAsync (same HW fill path, ~13us for 84MB, graph-capturable as a
// memset node); the kernel keeps only: x-read, layer-1, gates, and the rare
// cooperative dense path writing ~60KB of spiking rows. Stream order makes
// memset -> kernel-write ordering automatic (s_waitcnt hack removed).
//
// All computational forms verbatim-verified (absmax 0.0): packed-v2f
// layer-1 chain (R6/R7/R12/R14/R15), shuffle-tree colmax (R14/R15; fmax
// exactly associative -> values identical to serial scan), gate-1/gate-2
// (R5-R15; fp sum err <= 31*2^-24*Sum|terms| ~ 4e-5 << 2e-3 margin),
// cooperative dense path (R11-R15; predicated +0.0 IEEE identity,
// ascending i), serial tail (R4-R15; writes only gated non-zero outputs --
// memset provides the zeros).

typedef float v4f __attribute__((ext_vector_type(4)));
typedef float v2f __attribute__((ext_vector_type(2)));

#define TPB 256
#define TROWS 64               // rows per wave (1 per lane)
#define RPB (TPB * 1)          // 256 rows per block

__global__ __launch_bounds__(TPB) void snn_one(
    const float* __restrict__ x,
    const float* __restrict__ W1,   // [32,5]
    const float* __restrict__ W2,   // [32,32]
    const float* __restrict__ W3,   // [16,32]
    const float* __restrict__ W4,   // [10,16]
    float* __restrict__ out,        // [B,10] (pre-zeroed by memset)
    int B)
{
    __shared__ __align__(16) float xsh[4][TROWS * 5];   // 5KB: wave-private x
    __shared__ __align__(16) float smxl[4][32];         // per-wave colmax

    const int t = threadIdx.x;
    const int wv = t >> 6, lane = t & 63;
    float* sb = xsh[wv];
    const long wt0 = (long)blockIdx.x * RPB + (long)wv * TROWS;
    if (wt0 >= B) return;

    const bool full = (wt0 + TROWS <= B);

    // ---- (1) x loads first: 320 floats = 80 v4f per wave ----
    v4f g0, g1;
    if (full) {
        const v4f* xg = (const v4f*)(x + wt0 * 5);
        g0 = xg[lane];
        if (lane < 16) g1 = xg[64 + lane];
    }

    // ---- (2) W2 coalesced loads (consumed late, after layer-1) ----
    v4f wm0, wm1, wm2, wm3;
    {
        const v4f* w2g = (const v4f*)W2;
        wm0 = w2g[lane];
        wm1 = w2g[64 + lane];
        wm2 = w2g[128 + lane];
        wm3 = w2g[192 + lane];
    }

    // ---- (3) colmax shuffle tree + mxmax (exact; wave-uniform) ----
    // (placed here so both full and tail paths share it; W2 latency still
    //  hides under the independent x-load/LDS work the scheduler hoists)
    float mxmax;
    v4f vm;
    {
        vm.x = fmaxf(fmaxf(wm0.x, wm1.x), fmaxf(wm2.x, wm3.x));
        vm.y = fmaxf(fmaxf(wm0.y, wm1.y), fmaxf(wm2.y, wm3.y));
        vm.z = fmaxf(fmaxf(wm0.z, wm1.z), fmaxf(wm2.z, wm3.z));
        vm.w = fmaxf(fmaxf(wm0.w, wm1.w), fmaxf(wm2.w, wm3.w));
#pragma unroll
        for (int off = 8; off <= 32; off <<= 1) {
            vm.x = fmaxf(vm.x, __shfl_xor(vm.x, off));
            vm.y = fmaxf(vm.y, __shfl_xor(vm.y, off));
            vm.z = fmaxf(vm.z, __shfl_xor(vm.z, off));
            vm.w = fmaxf(vm.w, __shfl_xor(vm.w, off));
        }
        if (lane < 8) *(v4f*)(&smxl[wv][4 * lane]) = vm;
        float mx = fmaxf(fmaxf(vm.x, vm.y), fmaxf(vm.z, vm.w));
#pragma unroll
        for (int off = 1; off <= 4; off <<= 1)
            mx = fmaxf(mx, __shfl_xor(mx, off));
        mxmax = mx;
    }
    const float* __restrict__ smx = smxl[wv];

    if (full) {
        // ---- (4) stage x -> wave-private LDS, read back own row ----
        v4f* s4 = (v4f*)sb;
        s4[lane] = g0;
        if (lane < 16) s4[64 + lane] = g1;

        float xf[5];
        {
            const float* sx = sb + lane * 5;   // stride-5 banks: 2-way, free
#pragma unroll
            for (int e = 0; e < 5; ++e) xf[e] = sx[e];
        }

        // ---- (5) layer 1: packed v2f, j2-outer (verified form) ----
        unsigned m = 0u;
#pragma unroll
        for (int j2 = 0; j2 < 16; ++j2) {
            const float* wA = W1 + (2 * j2) * 5;
            const float* wB = W1 + (2 * j2 + 1) * 5;
            const v2f w0 = {wA[0], wB[0]};
            const v2f w1 = {wA[1], wB[1]};
            const v2f w2 = {wA[2], wB[2]};
            const v2f w3 = {wA[3], wB[3]};
            const v2f w4 = {wA[4], wB[4]};
            v2f h = xf[0] * w0;   // exact per-neuron chain order
            h += xf[1] * w1;
            h += xf[2] * w2;
            h += xf[3] * w3;
            h += xf[4] * w4;
            if (h.x >= 2.0f) m |= (1u << (2 * j2));
            if (h.y >= 2.0f) m |= (1u << (2 * j2 + 1));
        }

        // ---- (6) gates (verbatim R12/R14/R15 form) ----
        bool dense = false;
        if (m && ((float)__popc(m) * mxmax >= 1.998f)) {
            float S = 0.0f;
            unsigned mm = m;
            while (mm) { int i = __ffs(mm) - 1; mm &= mm - 1; S += smx[i]; }
            dense = (S >= 1.998f);
        }

        // ---- (7) cooperative dense path (verbatim R11-R15); only
        //          non-zero rows written (memset provided the zeros) ----
        if (__any(dense)) {
            v4f w2r[8];
            {
                const v4f* wr = (const v4f*)(W2 + (lane & 31) * 32);
#pragma unroll
                for (int e = 0; e < 8; ++e) w2r[e] = wr[e];
            }
            const float* w2f = (const float*)w2r;

            unsigned long long dmask = __ballot(dense);
            while (dmask) {
                const int L = (int)__ffsll(dmask) - 1;
                dmask &= dmask - 1;
                const unsigned mrow = __shfl(m, L);   // uniform bcast

                // h2[j] for j=lane (lanes 0..31), ascending i,
                // predicated +0.0 identity == verified skip form
                float h2 = 0.0f;
#pragma unroll
                for (int i = 0; i < 32; ++i)
                    h2 += ((mrow >> i) & 1u) ? w2f[i] : 0.0f;
                const unsigned m2 =
                    (unsigned)__ballot(lane < 32 && h2 >= 2.0f);

                if (m2) {   // ultra-rare
                    float g3 = 0.0f;
                    if (lane < 16) {
                        const float* w3r = W3 + lane * 32;
#pragma unroll
                        for (int i = 0; i < 32; ++i)
                            g3 += ((m2 >> i) & 1u) ? w3r[i] : 0.0f;
                    }
                    const unsigned m3 =
                        (unsigned)__ballot(lane < 16 && g3 >= 2.0f);
                    if (m3) {
                        float g4 = 0.0f;
                        if (lane < 10) {
                            const float* w4r = W4 + lane * 16;
#pragma unroll
                            for (int i = 0; i < 16; ++i)
                                g4 += ((m3 >> i) & 1u) ? w4r[i] : 0.0f;
                        }
                        if (lane < 10)
                            out[(wt0 + (long)L) * 10 + lane] =
                                (g4 >= 2.0f) ? 1.0f : 0.0f;
                    }
                }
            }
        }
    } else {
        // ---- tail wave (not hit at B=2^21; correctness-general, serial);
        //      writes only non-zero outputs (memset zeroed the rest) ----
        const long r = wt0 + (long)lane;
        if (r < B) {
            float xr[5];
#pragma unroll
            for (int k = 0; k < 5; ++k) xr[k] = x[r * 5 + k];
            unsigned mc = 0u;
#pragma unroll
            for (int j = 0; j < 32; ++j) {
                const float* w = W1 + j * 5;
                float h = xr[0] * w[0];
                h += xr[1] * w[1];
                h += xr[2] * w[2];
                h += xr[3] * w[3];
                h += xr[4] * w[4];
                if (h >= 2.0f) mc |= (1u << j);
            }
            if (mc && ((float)__popc(mc) * mxmax >= 1.998f)) {
                float S = 0.0f;
                unsigned mm = mc;
                while (mm) { int i = __ffs(mm) - 1; mm &= mm - 1; S += smx[i]; }
                if (S >= 1.998f) {
                    // serial dense: VERBATIM verified ascending set-bit order
                    float h2[32];
#pragma unroll
                    for (int j = 0; j < 32; ++j) h2[j] = 0.0f;
                    mm = mc;
                    while (mm) {
                        const int i = __ffs(mm) - 1;
                        mm &= mm - 1;
                        const float* colp = W2 + i;   // W2^T[i][j] == W2[j*32+i]
#pragma unroll
                        for (int j = 0; j < 32; ++j) h2[j] += colp[j * 32];
                    }
                    unsigned m2 = 0u;
#pragma unroll
                    for (int j = 0; j < 32; ++j)
                        if (h2[j] >= 2.0f) m2 |= (1u << j);
                    if (m2) {
                        unsigned m3 = 0u;
#pragma unroll
                        for (int j = 0; j < 16; ++j) {
                            float gg = 0.0f;
#pragma unroll
                            for (int i = 0; i < 32; ++i)
                                if ((m2 >> i) & 1u) gg += W3[j * 32 + i];
                            if (gg >= 2.0f) m3 |= (1u << j);
                        }
#pragma unroll
                        for (int j = 0; j < 10; ++j) {
                            float gg = 0.0f;
#pragma unroll
                            for (int i = 0; i < 16; ++i)
                                if ((m3 >> i) & 1u) gg += W4[j * 16 + i];
                            if (gg >= 2.0f) out[r * 10 + j] = 1.0f;
                        }
                    }
                }
            }
        }
    }
}

extern "C" void kernel_launch(void* const* d_in, const int* in_sizes, int n_in,
                              void* d_out, int out_size, void* d_ws, size_t ws_size,
                              hipStream_t stream) {
    const float* x  = (const float*)d_in[0];
    const float* W1 = (const float*)d_in[1];
    const float* W2 = (const float*)d_in[2];
    const float* W3 = (const float*)d_in[3];
    const float* W4 = (const float*)d_in[4];
    float* out = (float*)d_out;

    int B = in_sizes[0] / 5;
    // zeros via the HW fill path (~6.5 TB/s measured on this harness's own
    // re-poison fills); stream-ordered before the compute kernel, and
    // graph-capturable (memset node).
    hipMemsetAsync(out, 0, (size_t)out_size, stream);
    int grid = (B + RPB - 1) / RPB;
    snn_one<<<grid, TPB, 0, stream>>>(x, W1, W2, W3, W4, out, B);
}